// Round 1
// baseline (131.027 us; speedup 1.0000x reference)
//
#include <hip/hip_runtime.h>
#include <hip/hip_cooperative_groups.h>
#include <math.h>

#define B 512
#define D 256
#define MARGIN 0.3f
#define UW 0.05f
#define MIN_U 1e-6f
#define EPS 1e-8f

#define TI 16   // anchor rows per block
#define TJ 64   // candidate cols per block
#define BK 64   // k-chunk
#define NJT (B / TJ)   // 8 j-tiles

typedef unsigned long long ull;
namespace cg = cooperative_groups;

// ws layout (no init required -- every slot written before read):
//   [0,      32768)  ull pmax_part[NJT][B]
//   [32768,  65536)  ull nmin_part[NJT][B]
//   [65536,  68608)  float blk_part[256][3]  (loss_sum, n_valid, u_sum)

static __device__ inline ull shfl_xor_u64(ull v, int m) {
    unsigned int lo = (unsigned int)v;
    unsigned int hi = (unsigned int)(v >> 32);
    lo = __shfl_xor(lo, m, 64);
    hi = __shfl_xor(hi, m, 64);
    return ((ull)hi << 32) | lo;
}

static __device__ inline ull bcast_u64_lane0(ull v) {
    unsigned int lo = (unsigned int)v;
    unsigned int hi = (unsigned int)(v >> 32);
    lo = (unsigned int)__shfl((int)lo, 0, 64);
    hi = (unsigned int)__shfl((int)hi, 0, 64);
    return ((ull)hi << 32) | lo;
}

__global__ __launch_bounds__(256) void fused(const float* __restrict__ emb,
                                             const float* __restrict__ unc,
                                             const int* __restrict__ labels,
                                             ull* __restrict__ pmax_part,
                                             ull* __restrict__ nmin_part,
                                             float* __restrict__ blk_part,
                                             float* __restrict__ out) {
    const int bid = blockIdx.x;          // 0..255
    const int jt = bid & (NJT - 1);      // 0..7
    const int it = bid >> 3;             // 0..31
    const int t  = threadIdx.x;
    const int row  = t >> 4;
    const int col4 = (t & 15) * 4;

    __shared__ float As[BK][TI + 1];
    __shared__ float Bs[BK][TJ + 4];
    __shared__ int labI[TI], labJ[TJ];
    __shared__ float red[2][3];
    __shared__ float fred[4][3];

    // ---------------- phase 1: distance tile + hardest-pos/neg mining ----------------
    const int gi0 = it * TI;
    const int gj0 = jt * TJ;
    if (t < TI) labI[t] = labels[gi0 + t];
    if (t < TJ) labJ[t] = labels[gj0 + t];

    float a0 = 0.f, a1 = 0.f, a2 = 0.f, a3 = 0.f;

    for (int kc = 0; kc < D; kc += BK) {
        __syncthreads();
        {
            const int r = t >> 4;
            const int f = t & 15;
            float4 v = *reinterpret_cast<const float4*>(&emb[(size_t)(gi0 + r) * D + kc + f * 4]);
            As[f * 4 + 0][r] = v.x;
            As[f * 4 + 1][r] = v.y;
            As[f * 4 + 2][r] = v.z;
            As[f * 4 + 3][r] = v.w;
        }
#pragma unroll
        for (int g = 0; g < 4; ++g) {
            const int r = g * 16 + (t >> 4);
            const int f = t & 15;
            float4 v = *reinterpret_cast<const float4*>(&emb[(size_t)(gj0 + r) * D + kc + f * 4]);
            Bs[f * 4 + 0][r] = v.x;
            Bs[f * 4 + 1][r] = v.y;
            Bs[f * 4 + 2][r] = v.z;
            Bs[f * 4 + 3][r] = v.w;
        }
        __syncthreads();
#pragma unroll 8
        for (int k = 0; k < BK; ++k) {
            float a = As[k][row];
            float4 b = *reinterpret_cast<const float4*>(&Bs[k][col4]);
            float d;
            d = a - b.x; a0 = fmaf(d, d, a0);
            d = a - b.y; a1 = fmaf(d, d, a1);
            d = a - b.z; a2 = fmaf(d, d, a2);
            d = a - b.w; a3 = fmaf(d, d, a3);
        }
    }

    {
        const int gi = gi0 + row;
        const int li = labI[row];
        ull pbest = 0ull;
        ull nbest = ~0ull;
        float accs[4] = {a0, a1, a2, a3};
#pragma unroll
        for (int c = 0; c < 4; ++c) {
            const int jj = col4 + c;
            const int gj = gj0 + jj;
            const float dist = sqrtf(accs[c]) + EPS;
            const int lj = labJ[jj];
            const ull fb = (ull)__float_as_uint(dist) << 32;
            if (li == lj && gi != gj) {
                ull e = fb | (unsigned int)(0xFFFFFFFFu - (unsigned int)gj);
                pbest = pbest > e ? pbest : e;   // larger dist wins; tie -> smaller j
            }
            if (li != lj) {
                ull e = fb | (unsigned int)gj;
                nbest = nbest < e ? nbest : e;   // smaller dist wins; tie -> smaller j
            }
        }
        // reduce across the 16 consecutive lanes sharing this row
#pragma unroll
        for (int m = 1; m < 16; m <<= 1) {
            ull p2 = shfl_xor_u64(pbest, m);
            ull n2 = shfl_xor_u64(nbest, m);
            pbest = pbest > p2 ? pbest : p2;
            nbest = nbest < n2 ? nbest : n2;
        }
        if ((t & 15) == 0) {
            // agent-scope stores: visible across XCDs after grid sync
            __hip_atomic_store(&pmax_part[(size_t)jt * B + gi], pbest, __ATOMIC_RELAXED, __HIP_MEMORY_SCOPE_AGENT);
            __hip_atomic_store(&nmin_part[(size_t)jt * B + gi], nbest, __ATOMIC_RELAXED, __HIP_MEMORY_SCOPE_AGENT);
        }
    }

    cg::this_grid().sync();

    // ---------------- phase 2: per-anchor finalize (waves 0,1 -> anchors 2*bid, 2*bid+1) ----------------
    const int wave = t >> 6;   // 0..3
    const int lane = t & 63;

    if (wave < 2) {
        const int i = bid * 2 + wave;   // 0..511
        float loss_sum = 0.f, nval = 0.f, usum = 0.f;

        ull pe = 0ull, ne = ~0ull;
        if (lane < NJT) {
            pe = __hip_atomic_load(&pmax_part[(size_t)lane * B + i], __ATOMIC_RELAXED, __HIP_MEMORY_SCOPE_AGENT);
            ne = __hip_atomic_load(&nmin_part[(size_t)lane * B + i], __ATOMIC_RELAXED, __HIP_MEMORY_SCOPE_AGENT);
        }
#pragma unroll
        for (int m = 1; m < NJT; m <<= 1) {
            ull p2 = shfl_xor_u64(pe, m);
            ull n2 = shfl_xor_u64(ne, m);
            pe = pe > p2 ? pe : p2;
            ne = ne < n2 ? ne : n2;
        }
        pe = bcast_u64_lane0(pe);
        ne = bcast_u64_lane0(ne);

        const bool valid = (pe != 0ull) && (ne != ~0ull);
        const int jp = valid ? (int)(0xFFFFFFFFu - (unsigned int)pe) : i;
        const int jn = valid ? (int)(unsigned int)ne : i;
        const float dp = __uint_as_float((unsigned int)(pe >> 32));
        const float dn = __uint_as_float((unsigned int)(ne >> 32));

        const float4* emb4 = reinterpret_cast<const float4*>(emb);
        const float4* unc4 = reinterpret_cast<const float4*>(unc);
        float4 e = emb4[(size_t)i * 64 + lane];
        float4 u = unc4[(size_t)i * 64 + lane];
        float4 p = emb4[(size_t)jp * 64 + lane];
        float4 n = emb4[(size_t)jn * 64 + lane];
        float ux = fminf(fmaxf(u.x, MIN_U), 1.0f);
        float uy = fminf(fmaxf(u.y, MIN_U), 1.0f);
        float uz = fminf(fmaxf(u.z, MIN_U), 1.0f);
        float uw_ = fminf(fmaxf(u.w, MIN_U), 1.0f);

        float s0, s1, s2, d;
        d = e.x - p.x; s0 = ux * ux * d * d;
        d = e.y - p.y; s0 = fmaf(uy * uy, d * d, s0);
        d = e.z - p.z; s0 = fmaf(uz * uz, d * d, s0);
        d = e.w - p.w; s0 = fmaf(uw_ * uw_, d * d, s0);
        d = e.x - n.x; s1 = ux * ux * d * d;
        d = e.y - n.y; s1 = fmaf(uy * uy, d * d, s1);
        d = e.z - n.z; s1 = fmaf(uz * uz, d * d, s1);
        d = e.w - n.w; s1 = fmaf(uw_ * uw_, d * d, s1);
        s2 = ux + uy + uz + uw_;

#pragma unroll
        for (int m = 1; m < 64; m <<= 1) {
            s0 += __shfl_xor(s0, m, 64);
            s1 += __shfl_xor(s1, m, 64);
            s2 += __shfl_xor(s2, m, 64);
        }

        if (lane == 0) {
            usum = s2;
            if (valid) {
                const float up2 = s0 / (dp * dp) + EPS;
                const float un2 = s1 / (dn * dn) + EPS;
                const float sigma = sqrtf(up2 + un2 + EPS);
                const float z = (dp - dn + MARGIN + UW * sigma) / sigma;  // T=1
                const float sp = fmaxf(z, 0.f) + log1pf(expf(-fabsf(z)));
                loss_sum = sigma * sp;
                nval = 1.0f;
            }
            red[wave][0] = loss_sum;
            red[wave][1] = nval;
            red[wave][2] = usum;
        }
    }
    __syncthreads();
    if (t == 0) {
        __hip_atomic_store(&blk_part[bid * 3 + 0], red[0][0] + red[1][0], __ATOMIC_RELAXED, __HIP_MEMORY_SCOPE_AGENT);
        __hip_atomic_store(&blk_part[bid * 3 + 1], red[0][1] + red[1][1], __ATOMIC_RELAXED, __HIP_MEMORY_SCOPE_AGENT);
        __hip_atomic_store(&blk_part[bid * 3 + 2], red[0][2] + red[1][2], __ATOMIC_RELAXED, __HIP_MEMORY_SCOPE_AGENT);
    }

    cg::this_grid().sync();

    // ---------------- phase 3: block 0 reduces the 256 block partials ----------------
    if (bid == 0) {
        float l = __hip_atomic_load(&blk_part[t * 3 + 0], __ATOMIC_RELAXED, __HIP_MEMORY_SCOPE_AGENT);
        float v = __hip_atomic_load(&blk_part[t * 3 + 1], __ATOMIC_RELAXED, __HIP_MEMORY_SCOPE_AGENT);
        float s = __hip_atomic_load(&blk_part[t * 3 + 2], __ATOMIC_RELAXED, __HIP_MEMORY_SCOPE_AGENT);
#pragma unroll
        for (int m = 1; m < 64; m <<= 1) {
            l += __shfl_xor(l, m, 64);
            v += __shfl_xor(v, m, 64);
            s += __shfl_xor(s, m, 64);
        }
        if (lane == 0) {
            fred[wave][0] = l;
            fred[wave][1] = v;
            fred[wave][2] = s;
        }
        __syncthreads();
        if (t == 0) {
            l = fred[0][0] + fred[1][0] + fred[2][0] + fred[3][0];
            v = fred[0][1] + fred[1][1] + fred[2][1] + fred[3][1];
            s = fred[0][2] + fred[1][2] + fred[2][2] + fred[3][2];
            float total = l / fmaxf(v, 1.0f) + UW * (s / (float)(B * D));
            if (!isfinite(total)) total = 0.f;
            out[0] = total;
        }
    }
}

extern "C" void kernel_launch(void* const* d_in, const int* in_sizes, int n_in,
                              void* d_out, int out_size, void* d_ws, size_t ws_size,
                              hipStream_t stream) {
    const float* emb = (const float*)d_in[0];
    const float* unc = (const float*)d_in[1];
    const int* labels = (const int*)d_in[2];
    float* out = (float*)d_out;

    char* ws = (char*)d_ws;
    ull* pmax_part = (ull*)(ws);
    ull* nmin_part = (ull*)(ws + 32768);
    float* blk_part = (float*)(ws + 65536);

    void* args[] = {(void*)&emb, (void*)&unc, (void*)&labels,
                    (void*)&pmax_part, (void*)&nmin_part, (void*)&blk_part, (void*)&out};
    hipLaunchCooperativeKernel((void*)fused, dim3(256), dim3(256), args, 0, stream);
}

// Round 2
// 72.474 us; speedup vs baseline: 1.8079x; 1.8079x over previous
//
#include <hip/hip_runtime.h>
#include <math.h>

#define B 512
#define D 256
#define MARGIN 0.3f
#define UW 0.05f
#define MIN_U 1e-6f
#define EPS 1e-8f

#define TI 16   // anchor rows per block
#define TJ 64   // candidate cols per block
#define BK 64   // k-chunk
#define NJT (B / TJ)   // 8 j-tiles

typedef unsigned long long ull;

// ws layout (no init required -- every slot written before read):
//   [0,      32768)  ull pmax_part[NJT][B]
//   [32768,  65536)  ull nmin_part[NJT][B]
//   [65536,  68608)  float blk_part[256][3]  (loss_sum, n_valid, u_sum)

// Barrier counters as device globals: zero-initialized at module load.
// Monotonic-ticket protocol => no reset needed across graph replays:
//   each octet counter gets exactly 8 increments per launch, g_done gets 256.
__device__ unsigned int g_oct[32 * 16];   // one counter per 64B line (avoid line contention)
__device__ unsigned int g_done;

static __device__ inline ull shfl_xor_u64(ull v, int m) {
    unsigned int lo = (unsigned int)v;
    unsigned int hi = (unsigned int)(v >> 32);
    lo = __shfl_xor(lo, m, 64);
    hi = __shfl_xor(hi, m, 64);
    return ((ull)hi << 32) | lo;
}

static __device__ inline ull bcast_u64_lane0(ull v) {
    unsigned int lo = (unsigned int)v;
    unsigned int hi = (unsigned int)(v >> 32);
    lo = (unsigned int)__shfl((int)lo, 0, 64);
    hi = (unsigned int)__shfl((int)hi, 0, 64);
    return ((ull)hi << 32) | lo;
}

static __device__ inline void st_agent_u64(ull* p, ull v) {
    __hip_atomic_store(p, v, __ATOMIC_RELAXED, __HIP_MEMORY_SCOPE_AGENT);
}
static __device__ inline ull ld_agent_u64(const ull* p) {
    return __hip_atomic_load(p, __ATOMIC_RELAXED, __HIP_MEMORY_SCOPE_AGENT);
}
static __device__ inline void st_agent_f32(float* p, float v) {
    __hip_atomic_store(p, v, __ATOMIC_RELAXED, __HIP_MEMORY_SCOPE_AGENT);
}
static __device__ inline float ld_agent_f32(const float* p) {
    return __hip_atomic_load(p, __ATOMIC_RELAXED, __HIP_MEMORY_SCOPE_AGENT);
}

__global__ __launch_bounds__(256) void fused(const float* __restrict__ emb,
                                             const float* __restrict__ unc,
                                             const int* __restrict__ labels,
                                             ull* __restrict__ pmax_part,
                                             ull* __restrict__ nmin_part,
                                             float* __restrict__ blk_part,
                                             float* __restrict__ out) {
    const int bid = blockIdx.x;          // 0..255
    const int jt = bid & (NJT - 1);      // 0..7
    const int it = bid >> 3;             // 0..31
    const int t  = threadIdx.x;
    const int row  = t >> 4;
    const int col4 = (t & 15) * 4;

    __shared__ float As[BK][TI + 1];
    __shared__ float Bs[BK][TJ + 4];
    __shared__ int labI[TI], labJ[TJ];
    __shared__ float red[2][3];
    __shared__ float fred[4][3];
    __shared__ int s_last;

    // ---------------- phase 1: distance tile + hardest-pos/neg mining ----------------
    const int gi0 = it * TI;
    const int gj0 = jt * TJ;
    if (t < TI) labI[t] = labels[gi0 + t];
    if (t < TJ) labJ[t] = labels[gj0 + t];

    float a0 = 0.f, a1 = 0.f, a2 = 0.f, a3 = 0.f;

    for (int kc = 0; kc < D; kc += BK) {
        __syncthreads();
        {
            const int r = t >> 4;
            const int f = t & 15;
            float4 v = *reinterpret_cast<const float4*>(&emb[(size_t)(gi0 + r) * D + kc + f * 4]);
            As[f * 4 + 0][r] = v.x;
            As[f * 4 + 1][r] = v.y;
            As[f * 4 + 2][r] = v.z;
            As[f * 4 + 3][r] = v.w;
        }
#pragma unroll
        for (int g = 0; g < 4; ++g) {
            const int r = g * 16 + (t >> 4);
            const int f = t & 15;
            float4 v = *reinterpret_cast<const float4*>(&emb[(size_t)(gj0 + r) * D + kc + f * 4]);
            Bs[f * 4 + 0][r] = v.x;
            Bs[f * 4 + 1][r] = v.y;
            Bs[f * 4 + 2][r] = v.z;
            Bs[f * 4 + 3][r] = v.w;
        }
        __syncthreads();
#pragma unroll 8
        for (int k = 0; k < BK; ++k) {
            float a = As[k][row];
            float4 b = *reinterpret_cast<const float4*>(&Bs[k][col4]);
            float d;
            d = a - b.x; a0 = fmaf(d, d, a0);
            d = a - b.y; a1 = fmaf(d, d, a1);
            d = a - b.z; a2 = fmaf(d, d, a2);
            d = a - b.w; a3 = fmaf(d, d, a3);
        }
    }

    {
        const int gi = gi0 + row;
        const int li = labI[row];
        ull pbest = 0ull;
        ull nbest = ~0ull;
        float accs[4] = {a0, a1, a2, a3};
#pragma unroll
        for (int c = 0; c < 4; ++c) {
            const int jj = col4 + c;
            const int gj = gj0 + jj;
            const float dist = sqrtf(accs[c]) + EPS;
            const int lj = labJ[jj];
            const ull fb = (ull)__float_as_uint(dist) << 32;
            if (li == lj && gi != gj) {
                ull e = fb | (unsigned int)(0xFFFFFFFFu - (unsigned int)gj);
                pbest = pbest > e ? pbest : e;   // larger dist wins; tie -> smaller j
            }
            if (li != lj) {
                ull e = fb | (unsigned int)gj;
                nbest = nbest < e ? nbest : e;   // smaller dist wins; tie -> smaller j
            }
        }
        // reduce across the 16 consecutive lanes sharing this row
#pragma unroll
        for (int m = 1; m < 16; m <<= 1) {
            ull p2 = shfl_xor_u64(pbest, m);
            ull n2 = shfl_xor_u64(nbest, m);
            pbest = pbest > p2 ? pbest : p2;
            nbest = nbest < n2 ? nbest : n2;
        }
        if ((t & 15) == 0) {
            // agent-scope (sc1) stores go to the die-level coherence point
            st_agent_u64(&pmax_part[(size_t)jt * B + gi], pbest);
            st_agent_u64(&nmin_part[(size_t)jt * B + gi], nbest);
        }
    }

    // drain this wave's stores, then block barrier, then t0 joins the octet barrier
    asm volatile("s_waitcnt vmcnt(0)" ::: "memory");
    __syncthreads();

    // ---------------- octet barrier: the 8 blocks sharing this i-tile ----------------
    if (t == 0) {
        unsigned int ticket = __hip_atomic_fetch_add(&g_oct[it * 16], 1u,
                                                     __ATOMIC_RELAXED, __HIP_MEMORY_SCOPE_AGENT);
        unsigned int target = (ticket & ~7u) + 8u;   // tickets this launch are 8k..8k+7
        while ((int)(__hip_atomic_load(&g_oct[it * 16], __ATOMIC_RELAXED,
                                       __HIP_MEMORY_SCOPE_AGENT) - target) < 0) {
            __builtin_amdgcn_s_sleep(1);
        }
    }
    __syncthreads();

    // ---------------- phase 2: this block finalizes anchors gi0 + jt*2 + {0,1} ----------------
    const int wave = t >> 6;   // 0..3
    const int lane = t & 63;

    if (wave < 2) {
        const int i = gi0 + jt * 2 + wave;
        float loss_sum = 0.f, nval = 0.f, usum = 0.f;

        ull pe = 0ull, ne = ~0ull;
        if (lane < NJT) {
            pe = ld_agent_u64(&pmax_part[(size_t)lane * B + i]);
            ne = ld_agent_u64(&nmin_part[(size_t)lane * B + i]);
        }
#pragma unroll
        for (int m = 1; m < NJT; m <<= 1) {
            ull p2 = shfl_xor_u64(pe, m);
            ull n2 = shfl_xor_u64(ne, m);
            pe = pe > p2 ? pe : p2;
            ne = ne < n2 ? ne : n2;
        }
        pe = bcast_u64_lane0(pe);
        ne = bcast_u64_lane0(ne);

        const bool valid = (pe != 0ull) && (ne != ~0ull);
        const int jp = valid ? (int)(0xFFFFFFFFu - (unsigned int)pe) : i;
        const int jn = valid ? (int)(unsigned int)ne : i;
        const float dp = __uint_as_float((unsigned int)(pe >> 32));
        const float dn = __uint_as_float((unsigned int)(ne >> 32));

        const float4* emb4 = reinterpret_cast<const float4*>(emb);
        const float4* unc4 = reinterpret_cast<const float4*>(unc);
        float4 e = emb4[(size_t)i * 64 + lane];
        float4 u = unc4[(size_t)i * 64 + lane];
        float4 p = emb4[(size_t)jp * 64 + lane];
        float4 n = emb4[(size_t)jn * 64 + lane];
        float ux = fminf(fmaxf(u.x, MIN_U), 1.0f);
        float uy = fminf(fmaxf(u.y, MIN_U), 1.0f);
        float uz = fminf(fmaxf(u.z, MIN_U), 1.0f);
        float uw_ = fminf(fmaxf(u.w, MIN_U), 1.0f);

        float s0, s1, s2, d;
        d = e.x - p.x; s0 = ux * ux * d * d;
        d = e.y - p.y; s0 = fmaf(uy * uy, d * d, s0);
        d = e.z - p.z; s0 = fmaf(uz * uz, d * d, s0);
        d = e.w - p.w; s0 = fmaf(uw_ * uw_, d * d, s0);
        d = e.x - n.x; s1 = ux * ux * d * d;
        d = e.y - n.y; s1 = fmaf(uy * uy, d * d, s1);
        d = e.z - n.z; s1 = fmaf(uz * uz, d * d, s1);
        d = e.w - n.w; s1 = fmaf(uw_ * uw_, d * d, s1);
        s2 = ux + uy + uz + uw_;

#pragma unroll
        for (int m = 1; m < 64; m <<= 1) {
            s0 += __shfl_xor(s0, m, 64);
            s1 += __shfl_xor(s1, m, 64);
            s2 += __shfl_xor(s2, m, 64);
        }

        if (lane == 0) {
            usum = s2;
            if (valid) {
                const float up2 = s0 / (dp * dp) + EPS;
                const float un2 = s1 / (dn * dn) + EPS;
                const float sigma = sqrtf(up2 + un2 + EPS);
                const float z = (dp - dn + MARGIN + UW * sigma) / sigma;  // T=1
                const float sp = fmaxf(z, 0.f) + log1pf(expf(-fabsf(z)));
                loss_sum = sigma * sp;
                nval = 1.0f;
            }
            red[wave][0] = loss_sum;
            red[wave][1] = nval;
            red[wave][2] = usum;
        }
    }
    __syncthreads();

    // ---------------- block partials + last-done detection ----------------
    if (t == 0) {
        st_agent_f32(&blk_part[bid * 3 + 0], red[0][0] + red[1][0]);
        st_agent_f32(&blk_part[bid * 3 + 1], red[0][1] + red[1][1]);
        st_agent_f32(&blk_part[bid * 3 + 2], red[0][2] + red[1][2]);
        asm volatile("s_waitcnt vmcnt(0)" ::: "memory");
        unsigned int ticket = __hip_atomic_fetch_add(&g_done, 1u,
                                                     __ATOMIC_RELAXED, __HIP_MEMORY_SCOPE_AGENT);
        s_last = ((ticket & 255u) == 255u);   // 256 increments per launch
    }
    __syncthreads();

    // ---------------- last block: reduce the 256 block partials ----------------
    if (s_last) {
        float l = ld_agent_f32(&blk_part[t * 3 + 0]);
        float v = ld_agent_f32(&blk_part[t * 3 + 1]);
        float s = ld_agent_f32(&blk_part[t * 3 + 2]);
#pragma unroll
        for (int m = 1; m < 64; m <<= 1) {
            l += __shfl_xor(l, m, 64);
            v += __shfl_xor(v, m, 64);
            s += __shfl_xor(s, m, 64);
        }
        if (lane == 0) {
            fred[wave][0] = l;
            fred[wave][1] = v;
            fred[wave][2] = s;
        }
        __syncthreads();
        if (t == 0) {
            l = fred[0][0] + fred[1][0] + fred[2][0] + fred[3][0];
            v = fred[0][1] + fred[1][1] + fred[2][1] + fred[3][1];
            s = fred[0][2] + fred[1][2] + fred[2][2] + fred[3][2];
            float total = l / fmaxf(v, 1.0f) + UW * (s / (float)(B * D));
            if (!isfinite(total)) total = 0.f;
            out[0] = total;
        }
    }
}

extern "C" void kernel_launch(void* const* d_in, const int* in_sizes, int n_in,
                              void* d_out, int out_size, void* d_ws, size_t ws_size,
                              hipStream_t stream) {
    const float* emb = (const float*)d_in[0];
    const float* unc = (const float*)d_in[1];
    const int* labels = (const int*)d_in[2];
    float* out = (float*)d_out;

    char* ws = (char*)d_ws;
    ull* pmax_part = (ull*)(ws);
    ull* nmin_part = (ull*)(ws + 32768);
    float* blk_part = (float*)(ws + 65536);

    fused<<<256, 256, 0, stream>>>(emb, unc, labels, pmax_part, nmin_part, blk_part, out);
}